// Round 6
// baseline (982.460 us; speedup 1.0000x reference)
//
#include <hip/hip_runtime.h>
#include <stdint.h>

#define T_STEPS 512
#define BATCH   128
#define N_IN    256
#define N_H     1024
#define N_OUT   32

// ---------------- Kernel A: compact spike indices, 16 rows per block ----------------
// pairs[row][32] u32 words, each = idx_even | idx_odd<<16 (sentinel 256 -> zero
// row in the LDS weight tile); cnts[row] = active count (<=64).
__global__ __launch_bounds__(256) void k_prep(const float* __restrict__ spikes,
                                              uint32_t* __restrict__ pairs,
                                              uint32_t* __restrict__ cnts) {
    __shared__ uint16_t list[64];
    __shared__ uint32_t wcnt[4];
    const int tid = threadIdx.x;
    const int wave = tid >> 6, lane = tid & 63;
    for (int r = 0; r < 16; ++r) {
        const int row = blockIdx.x * 16 + r;       // t*BATCH + b
        float s = spikes[(size_t)row * N_IN + tid];
        bool act = s > 0.5f;                       // spikes are exactly 0.0/1.0
        unsigned long long m = __ballot(act);
        if (tid < 64) list[tid] = 256;             // sentinel
        if (lane == 0) wcnt[wave] = (uint32_t)__popcll(m);
        __syncthreads();
        uint32_t off = 0;
        for (int w = 0; w < wave; ++w) off += wcnt[w];
        uint32_t total = wcnt[0] + wcnt[1] + wcnt[2] + wcnt[3];
        if (act) {
            uint32_t pos = off + (uint32_t)__popcll(m & ((1ull << lane) - 1ull));
            if (pos < 64) list[pos] = (uint16_t)tid;   // ascending input index order
        }
        __syncthreads();
        if (tid < 32) {
            uint32_t w = (uint32_t)list[2 * tid] | ((uint32_t)list[2 * tid + 1] << 16);
            pairs[(size_t)row * 32 + tid] = w;
        }
        if (tid == 0) cnts[row] = total < 64u ? total : 64u;
        __syncthreads();
    }
}

// ---------------- Kernel T: transpose w_h[h][i] -> w_t[i][h] ----------------
__global__ __launch_bounds__(256) void k_tr(const float* __restrict__ w_h,
                                            float* __restrict__ w_t) {
    int gid = blockIdx.x * 256 + threadIdx.x;   // 262144 elements
    int h = gid >> 8, i = gid & 255;
    w_t[(size_t)i * N_H + h] = w_h[gid];
}

// ---------------- Kernel 12: fused sparse synapse + LIF scan ----------------
// Round-6 (= round-5 design, macro fixed): SCALAR index loads. b is wave-uniform
// (readfirstlane) -> index rows load via s_load into SGPRs (cannot spill; one
// 132-B fetch per wave per t through the scalar cache). Rounds 1-4 kept these
// per-lane: 16 MB/wave of scratch traffic (WRITE_SIZE tracked wave count).
// Geometry: block = 512 thr = 8 waves = 8 b sharing one tile wl[257][64]
// (row 256 = zeros). Grid = 16 bgroups x 16 htiles = 256 blocks.
// Lane l: h-duo d = l&31 (ds_read_b64), parity l>>5 splits the active list by
// position (same per-h add order as rounds 1-4 -> bit-identical spikes).
__global__ __launch_bounds__(512) void k_lif(const uint32_t* __restrict__ pairs,
                                             const uint32_t* __restrict__ cnts,
                                             const float* __restrict__ w_t,
                                             uint32_t* __restrict__ zmask) {
    extern __shared__ __align__(16) float wl[];   // 257*64 floats = 65,792 B
    const int bg = blockIdx.x >> 4, tile = blockIdx.x & 15;
    const int h0 = tile * 64, tid = threadIdx.x;

    #pragma unroll 8
    for (int k = 0; k < 8; ++k) {                 // 256 rows x 16 float4 = 4096
        int idx = (k << 9) + tid;
        int i = idx >> 4, c4 = (idx & 15) << 2;
        *(float4*)(wl + i * 64 + c4) =
            *(const float4*)(w_t + (size_t)i * N_H + h0 + c4);
    }
    if (tid < 64) wl[256 * 64 + tid] = 0.0f;      // sentinel row
    __syncthreads();

    const int wv = __builtin_amdgcn_readfirstlane(tid >> 6);  // PROVABLY uniform
    const int b  = (bg << 3) + wv;                // one b per wave, uniform
    const int l  = tid & 63;
    const int duo2 = (l & 31) << 1;               // float offset of h-duo
    const uint32_t vshift = (uint32_t)((l >> 5) << 4);  // parity: 0 or 16

    uint32_t cntc, cntn;
    uint4 C0, C1, C2, C3, C4, C5, C6, C7;         // scalar (SGPR) index sets
    uint4 N0, N1, N2, N3, N4, N5, N6, N7;

#define LOADC(ROW) { const uint4* wp = (const uint4*)(pairs + (size_t)(ROW) * 32); \
    cntc = cnts[ROW]; C0=wp[0]; C1=wp[1]; C2=wp[2]; C3=wp[3]; C4=wp[4]; C5=wp[5]; C6=wp[6]; C7=wp[7]; }
#define LOADN(ROW) { const uint4* wp = (const uint4*)(pairs + (size_t)(ROW) * 32); \
    cntn = cnts[ROW]; N0=wp[0]; N1=wp[1]; N2=wp[2]; N3=wp[3]; N4=wp[4]; N5=wp[5]; N6=wp[6]; N7=wp[7]; }
// GW accumulates into fixed-name locals gacc0/gacc1 declared by GATHER's scope
// (macro hygiene: GW's body tokens are NOT substituted by GATHER's params).
#define GW(J, WRD) if (cntc > (2u*(J))) { \
        uint32_t ia = ((WRD) >> vshift) & 0xFFFFu; \
        const float2 t2 = *(const float2*)(wl + ia * 64 + duo2); \
        gacc0 += t2.x; gacc1 += t2.y; }
#define GATHER(OUT0, OUT1) do { float gacc0 = 0.0f, gacc1 = 0.0f; \
        GW(0,C0.x)  GW(1,C0.y)  GW(2,C0.z)  GW(3,C0.w)  \
        GW(4,C1.x)  GW(5,C1.y)  GW(6,C1.z)  GW(7,C1.w)  \
        GW(8,C2.x)  GW(9,C2.y)  GW(10,C2.z) GW(11,C2.w) \
        GW(12,C3.x) GW(13,C3.y) GW(14,C3.z) GW(15,C3.w) \
        GW(16,C4.x) GW(17,C4.y) GW(18,C4.z) GW(19,C4.w) \
        GW(20,C5.x) GW(21,C5.y) GW(22,C5.z) GW(23,C5.w) \
        GW(24,C6.x) GW(25,C6.y) GW(26,C6.z) GW(27,C6.w) \
        GW(28,C7.x) GW(29,C7.y) GW(30,C7.z) GW(31,C7.w) \
        (OUT0) = gacc0; (OUT1) = gacc1; } while(0)

    float v0 = 0, v1 = 0, s0 = 0, s1 = 0;
    float c0, c1;
    LOADC(b);                            // idx(0)
    GATHER(c0, c1);                      // currents for t=0
    LOADC(BATCH + b);                    // idx(1) -> gathered inside iter t=0
    LOADN(2 * BATCH + b);                // idx(2)

    for (int t = 0; t < T_STEPS; ++t) {
        // combine parity halves (commutative add -> both lanes get identical c)
        c0 += __shfl_xor(c0, 32);
        c1 += __shfl_xor(c1, 32);

        float n0, n1;
        GATHER(n0, n1);                  // currents for t+1 (uses C = idx(t+1))

        // rotate C <- N, prefetch N <- idx(t+3)  (scalar moves + s_load)
        cntc = cntn; C0=N0; C1=N1; C2=N2; C3=N3; C4=N4; C5=N5; C6=N6; C7=N7;
        int rn = t + 3; if (rn > T_STEPS - 1) rn = T_STEPS - 1;
        LOADN(rn * BATCH + b);

        // LIF (fma forms locked to rounds 1-4 passing arithmetic)
        s0 = __builtin_fmaf(s0, 0.875f, c0);
        s1 = __builtin_fmaf(s1, 0.875f, c1);
        v0 = __builtin_fmaf(0.125f, s0 - v0, v0);
        v1 = __builtin_fmaf(0.125f, s1 - v1, v1);

        unsigned long long m0 = __ballot(v0 > 1.0f);   // low32: bit d -> h=h0+2d
        unsigned long long m1 = __ballot(v1 > 1.0f);   // low32: bit d -> h=h0+2d+1
        if (v0 > 1.0f) v0 = 0.0f;
        if (v1 > 1.0f) v1 = 0.0f;

        if (l == 0) {
            uint2* zp = (uint2*)(zmask + (size_t)(t * BATCH + b) * 32 + (tile << 1));
            *zp = make_uint2((uint32_t)m0, (uint32_t)m1);
        }
        c0 = n0; c1 = n1;
    }
#undef LOADC
#undef LOADN
#undef GW
#undef GATHER
}

// ---------------- Kernel 34: sparse output synapse + LI scan ----------------
// Round-6: block = (b, o-octet): 128 b x 4 = 512 blocks, 256 thr.
// Lane: o_local = tid>>5 (8 o), word = tid&31 (all 32 zmask words). Each out
// element is written by EXACTLY ONE lane -> no atomics, no d_out memset.
// zmask bit mapping: word w, bit j -> h = (w>>1)*64 + 2j + (w&1).
__global__ __launch_bounds__(256) void k_li(const uint32_t* __restrict__ zmask,
                                            const float* __restrict__ w_o,
                                            float* __restrict__ out) {
    extern __shared__ __align__(16) float wo[];   // 8 * 1025 floats = 32,800 B
    const int b  = blockIdx.x >> 2;
    const int o0 = (blockIdx.x & 3) << 3;
    const int tid = threadIdx.x;
    for (int lin = tid; lin < 8 * 1024; lin += 256) {
        int ol = lin >> 10, idx = lin & 1023;
        int word = idx >> 5, j = idx & 31;
        int h = ((word >> 1) << 6) + (j << 1) + (word & 1);
        wo[ol * 1025 + idx] = w_o[(size_t)(o0 + ol) * N_H + h];
    }
    __syncthreads();

    const int ol = tid >> 5, word = tid & 31;
    const float* wrow = wo + ol * 1025 + (word << 5);

    float v = 0.0f, s = 0.0f;
    uint32_t m_n = zmask[(size_t)b * 32 + word];
    for (int t = 0; t < T_STEPS; ++t) {
        uint32_t m = m_n;
        int tn = (t + 1 < T_STEPS) ? t + 1 : t;
        m_n = zmask[(size_t)(tn * BATCH + b) * 32 + word];

        float c = 0.0f;
        while (m) { int j = __builtin_ctz(m); m &= m - 1; c += wrow[j]; }

        // reduce over 32 word-lanes (stays within each 32-lane half: xor<=16)
        c += __shfl_xor(c, 1);
        c += __shfl_xor(c, 2);
        c += __shfl_xor(c, 4);
        c += __shfl_xor(c, 8);
        c += __shfl_xor(c, 16);

        s = __builtin_fmaf(s, 0.875f, c);
        v = __builtin_fmaf(0.125f, s - v, v);

        if (word == 0)
            out[(size_t)(t * BATCH + b) * 32 + o0 + ol] = v;
    }
}

// ---------------- launch ----------------
extern "C" void kernel_launch(void* const* d_in, const int* in_sizes, int n_in,
                              void* d_out, int out_size, void* d_ws, size_t ws_size,
                              hipStream_t stream) {
    const float* spikes = (const float*)d_in[0];
    const float* w_h    = (const float*)d_in[1];
    const float* w_o    = (const float*)d_in[2];
    float* out = (float*)d_out;

    char* ws = (char*)d_ws;
    uint32_t* pairs = (uint32_t*)(ws);                 // 8,388,608 B
    uint32_t* cnts  = (uint32_t*)(ws + 8388608);       //   262,144 B
    float*    w_t   = (float*)   (ws + 8650752);       // 1,048,576 B
    uint32_t* zmask = (uint32_t*)(ws + 9699328);       // 8,388,608 B

    const int lds12 = (256 * 64 + 64) * 4;   // 65,792 B -> 2 blocks/CU
    const int lds34 = 8 * 1025 * 4;          // 32,800 B
    hipFuncSetAttribute((const void*)k_lif, hipFuncAttributeMaxDynamicSharedMemorySize, lds12);
    hipFuncSetAttribute((const void*)k_li,  hipFuncAttributeMaxDynamicSharedMemorySize, lds34);

    k_prep<<<(T_STEPS * BATCH) / 16, 256, 0, stream>>>(spikes, pairs, cnts);
    k_tr<<<(N_H * N_IN) / 256, 256, 0, stream>>>(w_h, w_t);
    k_lif<<<256, 512, lds12, stream>>>(pairs, cnts, w_t, zmask);
    k_li<<<BATCH * 4, 256, lds34, stream>>>(zmask, w_o, out);
}

// Round 7
// 884.705 us; speedup vs baseline: 1.1105x; 1.1105x over previous
//
#include <hip/hip_runtime.h>
#include <stdint.h>

#define T_STEPS 512
#define BATCH   128
#define N_IN    256
#define N_H     1024
#define N_OUT   32

// ---------------- Kernel A: compact spike indices, 16 rows per block ----------------
// pairs[row][32] u32 words, each = idx_even | idx_odd<<16 (sentinel 256 -> zero
// row in the LDS weight tile); cnts[row] = active count (<=64).
__global__ __launch_bounds__(256) void k_prep(const float* __restrict__ spikes,
                                              uint32_t* __restrict__ pairs,
                                              uint32_t* __restrict__ cnts) {
    __shared__ uint16_t list[64];
    __shared__ uint32_t wcnt[4];
    const int tid = threadIdx.x;
    const int wave = tid >> 6, lane = tid & 63;
    for (int r = 0; r < 16; ++r) {
        const int row = blockIdx.x * 16 + r;       // t*BATCH + b
        float s = spikes[(size_t)row * N_IN + tid];
        bool act = s > 0.5f;                       // spikes are exactly 0.0/1.0
        unsigned long long m = __ballot(act);
        if (tid < 64) list[tid] = 256;             // sentinel
        if (lane == 0) wcnt[wave] = (uint32_t)__popcll(m);
        __syncthreads();
        uint32_t off = 0;
        for (int w = 0; w < wave; ++w) off += wcnt[w];
        uint32_t total = wcnt[0] + wcnt[1] + wcnt[2] + wcnt[3];
        if (act) {
            uint32_t pos = off + (uint32_t)__popcll(m & ((1ull << lane) - 1ull));
            if (pos < 64) list[pos] = (uint16_t)tid;   // ascending input index order
        }
        __syncthreads();
        if (tid < 32) {
            uint32_t w = (uint32_t)list[2 * tid] | ((uint32_t)list[2 * tid + 1] << 16);
            pairs[(size_t)row * 32 + tid] = w;
        }
        if (tid == 0) cnts[row] = total < 64u ? total : 64u;
        __syncthreads();
    }
}

// ---------------- Kernel T: transpose w_h[h][i] -> w_t[i][h] ----------------
__global__ __launch_bounds__(256) void k_tr(const float* __restrict__ w_h,
                                            float* __restrict__ w_t) {
    int gid = blockIdx.x * 256 + threadIdx.x;   // 262144 elements
    int h = gid >> 8, i = gid & 255;
    w_t[(size_t)i * N_H + h] = w_h[gid];
}

// ---------------- Kernel 12: fused sparse synapse + LIF scan ----------------
// Round-7: CHUNKED branchless gather. Round-6 had 32 scalar branches per
// gather, each guarding one ds_read -> loads can't hoist across branches ->
// ~900 cyc/wave-t exposed ds_read latency (VALUBusy 30%, wall 1446 cyc).
// Now: 8 chunks guarded at cnt>8c; each chunk = 4 UNCONDITIONAL independent
// ds_read_b64 (sentinel rows make over-read positions add +0.0 in the same
// per-lane sequence -> bit-identical sums). Indices stay in SGPRs (round-6).
__global__ __launch_bounds__(512) void k_lif(const uint32_t* __restrict__ pairs,
                                             const uint32_t* __restrict__ cnts,
                                             const float* __restrict__ w_t,
                                             uint32_t* __restrict__ zmask) {
    extern __shared__ __align__(16) float wl[];   // 257*64 floats = 65,792 B
    const int bg = blockIdx.x >> 4, tile = blockIdx.x & 15;
    const int h0 = tile * 64, tid = threadIdx.x;

    #pragma unroll 8
    for (int k = 0; k < 8; ++k) {                 // 256 rows x 16 float4 = 4096
        int idx = (k << 9) + tid;
        int i = idx >> 4, c4 = (idx & 15) << 2;
        *(float4*)(wl + i * 64 + c4) =
            *(const float4*)(w_t + (size_t)i * N_H + h0 + c4);
    }
    if (tid < 64) wl[256 * 64 + tid] = 0.0f;      // sentinel row
    __syncthreads();

    const int wv = __builtin_amdgcn_readfirstlane(tid >> 6);  // PROVABLY uniform
    const int b  = (bg << 3) + wv;                // one b per wave, uniform
    const int l  = tid & 63;
    const int duo2 = (l & 31) << 1;               // float offset of h-duo
    const uint32_t vshift = (uint32_t)((l >> 5) << 4);  // parity: 0 or 16

    uint32_t cntc, cntn;
    uint4 C0, C1, C2, C3, C4, C5, C6, C7;         // scalar (SGPR) index sets
    uint4 N0, N1, N2, N3, N4, N5, N6, N7;

#define LOADC(ROW) { const uint4* wp = (const uint4*)(pairs + (size_t)(ROW) * 32); \
    cntc = cnts[ROW]; C0=wp[0]; C1=wp[1]; C2=wp[2]; C3=wp[3]; C4=wp[4]; C5=wp[5]; C6=wp[6]; C7=wp[7]; }
#define LOADN(ROW) { const uint4* wp = (const uint4*)(pairs + (size_t)(ROW) * 32); \
    cntn = cnts[ROW]; N0=wp[0]; N1=wp[1]; N2=wp[2]; N3=wp[3]; N4=wp[4]; N5=wp[5]; N6=wp[6]; N7=wp[7]; }
// One chunk: 4 words -> 4 independent b64 reads issued before any accumulate.
// Adds stay in word order (same per-lane sequence as round 6 -> bit-identical).
#define GCHUNK(CW) { \
        uint32_t ia0 = ((CW).x >> vshift) & 0xFFFFu; \
        uint32_t ia1 = ((CW).y >> vshift) & 0xFFFFu; \
        uint32_t ia2 = ((CW).z >> vshift) & 0xFFFFu; \
        uint32_t ia3 = ((CW).w >> vshift) & 0xFFFFu; \
        const float2 r0 = *(const float2*)(wl + ia0 * 64 + duo2); \
        const float2 r1 = *(const float2*)(wl + ia1 * 64 + duo2); \
        const float2 r2 = *(const float2*)(wl + ia2 * 64 + duo2); \
        const float2 r3 = *(const float2*)(wl + ia3 * 64 + duo2); \
        gacc0 += r0.x; gacc1 += r0.y; \
        gacc0 += r1.x; gacc1 += r1.y; \
        gacc0 += r2.x; gacc1 += r2.y; \
        gacc0 += r3.x; gacc1 += r3.y; }
#define GATHER(OUT0, OUT1) do { float gacc0 = 0.0f, gacc1 = 0.0f; \
        GCHUNK(C0) \
        if (cntc >  8u) GCHUNK(C1) \
        if (cntc > 16u) GCHUNK(C2) \
        if (cntc > 24u) GCHUNK(C3) \
        if (cntc > 32u) { GCHUNK(C4) \
            if (cntc > 40u) GCHUNK(C5) \
            if (cntc > 48u) GCHUNK(C6) \
            if (cntc > 56u) GCHUNK(C7) } \
        (OUT0) = gacc0; (OUT1) = gacc1; } while(0)

    float v0 = 0, v1 = 0, s0 = 0, s1 = 0;
    float c0, c1;
    LOADC(b);                            // idx(0)
    GATHER(c0, c1);                      // currents for t=0
    LOADC(BATCH + b);                    // idx(1) -> gathered inside iter t=0
    LOADN(2 * BATCH + b);                // idx(2)

    for (int t = 0; t < T_STEPS; ++t) {
        // combine parity halves (commutative add -> both lanes get identical c)
        c0 += __shfl_xor(c0, 32);
        c1 += __shfl_xor(c1, 32);

        float n0, n1;
        GATHER(n0, n1);                  // currents for t+1 (uses C = idx(t+1))

        // rotate C <- N, prefetch N <- idx(t+3)  (scalar moves + s_load)
        cntc = cntn; C0=N0; C1=N1; C2=N2; C3=N3; C4=N4; C5=N5; C6=N6; C7=N7;
        int rn = t + 3; if (rn > T_STEPS - 1) rn = T_STEPS - 1;
        LOADN(rn * BATCH + b);

        // LIF (fma forms locked to rounds 1-6 passing arithmetic)
        s0 = __builtin_fmaf(s0, 0.875f, c0);
        s1 = __builtin_fmaf(s1, 0.875f, c1);
        v0 = __builtin_fmaf(0.125f, s0 - v0, v0);
        v1 = __builtin_fmaf(0.125f, s1 - v1, v1);

        unsigned long long m0 = __ballot(v0 > 1.0f);   // low32: bit d -> h=h0+2d
        unsigned long long m1 = __ballot(v1 > 1.0f);   // low32: bit d -> h=h0+2d+1
        if (v0 > 1.0f) v0 = 0.0f;
        if (v1 > 1.0f) v1 = 0.0f;

        if (l == 0) {
            uint2* zp = (uint2*)(zmask + (size_t)(t * BATCH + b) * 32 + (tile << 1));
            *zp = make_uint2((uint32_t)m0, (uint32_t)m1);
        }
        c0 = n0; c1 = n1;
    }
#undef LOADC
#undef LOADN
#undef GCHUNK
#undef GATHER
}

// ---------------- Kernel 34: output synapse + LI scan, VGPR-resident ----------------
// Round-7: round-6's while(ctz){LDS read} was a per-bit serialized latency
// chain with wave-max divergence (~max 8-9 trips x ~70 cyc). Now: lane =
// (o, word-half); its 32 w_o values are T-INVARIANT -> preloaded into VGPRs
// once; per t the mask applies via shift/ashr/and/add (4 VALU/bit, no LDS,
// no branches). 4 accumulators break the fp add chain (post-nonlinearity,
// linear path -> reassociation safe). Two b-halves partial-LI + atomicAdd
// (2 commutative adds = deterministic). Grid 128 b x 2 halves, 512 thr.
__global__ __launch_bounds__(512) void k_li(const uint32_t* __restrict__ zmask,
                                            const float* __restrict__ w_o,
                                            float* __restrict__ out) {
    const int b = blockIdx.x >> 1, half = blockIdx.x & 1;
    const int tid = threadIdx.x;
    const int o = tid >> 4, wq = tid & 15;
    const int word = half * 16 + wq;

    // zmask bit mapping: word w, bit j -> h = (w>>1)*64 + 2j + (w&1)
    float wreg[32];
    #pragma unroll
    for (int j = 0; j < 32; ++j) {
        int h = ((word >> 1) << 6) + (j << 1) + (word & 1);
        wreg[j] = w_o[(size_t)o * N_H + h];
    }

    float v = 0.0f, s = 0.0f;
    uint32_t m_n = zmask[(size_t)b * 32 + word];
    for (int t = 0; t < T_STEPS; ++t) {
        uint32_t m = m_n;
        int tn = (t + 1 < T_STEPS) ? t + 1 : t;
        m_n = zmask[(size_t)(tn * BATCH + b) * 32 + word];

        float a0 = 0.0f, a1 = 0.0f, a2 = 0.0f, a3 = 0.0f;
        #pragma unroll
        for (int j = 0; j < 32; j += 4) {
            uint32_t s0m = (uint32_t)((int32_t)(m << (31 - j))       >> 31);
            uint32_t s1m = (uint32_t)((int32_t)(m << (31 - (j + 1))) >> 31);
            uint32_t s2m = (uint32_t)((int32_t)(m << (31 - (j + 2))) >> 31);
            uint32_t s3m = (uint32_t)((int32_t)(m << (31 - (j + 3))) >> 31);
            a0 += __uint_as_float(s0m & __float_as_uint(wreg[j]));
            a1 += __uint_as_float(s1m & __float_as_uint(wreg[j + 1]));
            a2 += __uint_as_float(s2m & __float_as_uint(wreg[j + 2]));
            a3 += __uint_as_float(s3m & __float_as_uint(wreg[j + 3]));
        }
        float c = (a0 + a1) + (a2 + a3);

        // reduce over the 16 word-lanes of this o (xor<=8 stays in-group)
        c += __shfl_xor(c, 1);
        c += __shfl_xor(c, 2);
        c += __shfl_xor(c, 4);
        c += __shfl_xor(c, 8);

        s = __builtin_fmaf(s, 0.875f, c);
        v = __builtin_fmaf(0.125f, s - v, v);

        if (wq == 0)
            atomicAdd(out + (size_t)(t * BATCH + b) * 32 + o, v);
    }
}

// ---------------- launch ----------------
extern "C" void kernel_launch(void* const* d_in, const int* in_sizes, int n_in,
                              void* d_out, int out_size, void* d_ws, size_t ws_size,
                              hipStream_t stream) {
    const float* spikes = (const float*)d_in[0];
    const float* w_h    = (const float*)d_in[1];
    const float* w_o    = (const float*)d_in[2];
    float* out = (float*)d_out;

    char* ws = (char*)d_ws;
    uint32_t* pairs = (uint32_t*)(ws);                 // 8,388,608 B
    uint32_t* cnts  = (uint32_t*)(ws + 8388608);       //   262,144 B
    float*    w_t   = (float*)   (ws + 8650752);       // 1,048,576 B
    uint32_t* zmask = (uint32_t*)(ws + 9699328);       // 8,388,608 B

    const int lds12 = (256 * 64 + 64) * 4;   // 65,792 B
    hipFuncSetAttribute((const void*)k_lif, hipFuncAttributeMaxDynamicSharedMemorySize, lds12);

    hipMemsetAsync(d_out, 0, (size_t)out_size * sizeof(float), stream);
    k_prep<<<(T_STEPS * BATCH) / 16, 256, 0, stream>>>(spikes, pairs, cnts);
    k_tr<<<(N_H * N_IN) / 256, 256, 0, stream>>>(w_h, w_t);
    k_lif<<<256, 512, lds12, stream>>>(pairs, cnts, w_t, zmask);
    k_li<<<BATCH * 2, 512, 0, stream>>>(zmask, w_o, out);
}

// Round 8
// 629.215 us; speedup vs baseline: 1.5614x; 1.4060x over previous
//
#include <hip/hip_runtime.h>
#include <stdint.h>

#define T_STEPS 512
#define BATCH   128
#define N_IN    256
#define N_H     1024
#define N_OUT   32

// ---------------- Kernel A: compact spike indices, 16 rows per block ----------------
// pairs[row][32] u32 words, each = idx_even | idx_odd<<16 (sentinel 256 -> zero
// row in the LDS weight tile); cnts[row] = active count (<=64).
__global__ __launch_bounds__(256) void k_prep(const float* __restrict__ spikes,
                                              uint32_t* __restrict__ pairs,
                                              uint32_t* __restrict__ cnts) {
    __shared__ uint16_t list[64];
    __shared__ uint32_t wcnt[4];
    const int tid = threadIdx.x;
    const int wave = tid >> 6, lane = tid & 63;
    for (int r = 0; r < 16; ++r) {
        const int row = blockIdx.x * 16 + r;       // t*BATCH + b
        float s = spikes[(size_t)row * N_IN + tid];
        bool act = s > 0.5f;                       // spikes are exactly 0.0/1.0
        unsigned long long m = __ballot(act);
        if (tid < 64) list[tid] = 256;             // sentinel
        if (lane == 0) wcnt[wave] = (uint32_t)__popcll(m);
        __syncthreads();
        uint32_t off = 0;
        for (int w = 0; w < wave; ++w) off += wcnt[w];
        uint32_t total = wcnt[0] + wcnt[1] + wcnt[2] + wcnt[3];
        if (act) {
            uint32_t pos = off + (uint32_t)__popcll(m & ((1ull << lane) - 1ull));
            if (pos < 64) list[pos] = (uint16_t)tid;   // ascending input index order
        }
        __syncthreads();
        if (tid < 32) {
            uint32_t w = (uint32_t)list[2 * tid] | ((uint32_t)list[2 * tid + 1] << 16);
            pairs[(size_t)row * 32 + tid] = w;
        }
        if (tid == 0) cnts[row] = total < 64u ? total : 64u;
        __syncthreads();
    }
}

// ---------------- Kernel T: transpose w_h[h][i] -> w_t[i][h] ----------------
__global__ __launch_bounds__(256) void k_tr(const float* __restrict__ w_h,
                                            float* __restrict__ w_t) {
    int gid = blockIdx.x * 256 + threadIdx.x;   // 262144 elements
    int h = gid >> 8, i = gid & 255;
    w_t[(size_t)i * N_H + h] = w_h[gid];
}

// ---------------- Kernel 12: fused sparse synapse + LIF scan ----------------
// Round-8: 2x t-unroll, DUAL in-flight gathers. Gathers for t and t+1 are
// independent (only the LIF fma chain is sequential) -> two interleaved
// gather streams per iteration double memory-level parallelism at the same
// occupancy (r7 was latency-bound at 45% of its 196-us LDS pipe floor).
// Index sets slimmed to words 0..15 (cnt<=32 covers 94% of rows; scalar-
// branched tail reload otherwise) so FOUR sets fit in SGPRs.
// Per-t arithmetic order identical to r7 -> bit-identical spikes.
__global__ __launch_bounds__(512) void k_lif(const uint32_t* __restrict__ pairs,
                                             const uint32_t* __restrict__ cnts,
                                             const float* __restrict__ w_t,
                                             uint32_t* __restrict__ zmask) {
    extern __shared__ __align__(16) float wl[];   // 257*64 floats = 65,792 B
    const int bg = blockIdx.x >> 4, tile = blockIdx.x & 15;
    const int h0 = tile * 64, tid = threadIdx.x;

    #pragma unroll 8
    for (int k = 0; k < 8; ++k) {                 // 256 rows x 16 float4 = 4096
        int idx = (k << 9) + tid;
        int i = idx >> 4, c4 = (idx & 15) << 2;
        *(float4*)(wl + i * 64 + c4) =
            *(const float4*)(w_t + (size_t)i * N_H + h0 + c4);
    }
    if (tid < 64) wl[256 * 64 + tid] = 0.0f;      // sentinel row
    __syncthreads();

    const int wv = __builtin_amdgcn_readfirstlane(tid >> 6);  // uniform wave id
    const int b  = (bg << 3) + wv;                // one b per wave, uniform
    const int l  = tid & 63;
    const int duo2 = (l & 31) << 1;               // float offset of h-duo
    const uint32_t vshift = (uint32_t)((l >> 5) << 4);  // parity: 0 or 16

    uint32_t cA, cB, cC, cD;                      // scalar counts
    uint4 A0,A1,A2,A3, B0,B1,B2,B3, C0,C1,C2,C3, D0,D1,D2,D3;  // SGPR idx sets

#define LOADSET(CN, S0,S1,S2,S3, ROW) { \
    const uint4* wp = (const uint4*)(pairs + (size_t)(ROW) * 32); \
    CN = cnts[ROW]; S0 = wp[0]; S1 = wp[1]; S2 = wp[2]; S3 = wp[3]; }

#define GCHUNK(CW) { \
    uint32_t ia0 = ((CW).x >> vshift) & 0xFFFFu; \
    uint32_t ia1 = ((CW).y >> vshift) & 0xFFFFu; \
    uint32_t ia2 = ((CW).z >> vshift) & 0xFFFFu; \
    uint32_t ia3 = ((CW).w >> vshift) & 0xFFFFu; \
    const float2 r0 = *(const float2*)(wl + ia0 * 64 + duo2); \
    const float2 r1 = *(const float2*)(wl + ia1 * 64 + duo2); \
    const float2 r2 = *(const float2*)(wl + ia2 * 64 + duo2); \
    const float2 r3 = *(const float2*)(wl + ia3 * 64 + duo2); \
    gacc0 += r0.x; gacc1 += r0.y; gacc0 += r1.x; gacc1 += r1.y; \
    gacc0 += r2.x; gacc1 += r2.y; gacc0 += r3.x; gacc1 += r3.y; }

#define GATHER(OUT0, OUT1, CN, S0,S1,S2,S3, ROW) do { \
    float gacc0 = 0.0f, gacc1 = 0.0f; \
    uint32_t cs = __builtin_amdgcn_readfirstlane(CN); \
    GCHUNK(S0) \
    if (cs >  8u) GCHUNK(S1) \
    if (cs > 16u) GCHUNK(S2) \
    if (cs > 24u) GCHUNK(S3) \
    if (cs > 32u) { /* rare (~6%) tail: reload words 16..31 */ \
        const uint4* wp = (const uint4*)(pairs + (size_t)(ROW) * 32); \
        uint4 T4 = wp[4], T5 = wp[5], T6 = wp[6], T7 = wp[7]; \
        GCHUNK(T4) \
        if (cs > 40u) GCHUNK(T5) \
        if (cs > 48u) GCHUNK(T6) \
        if (cs > 56u) GCHUNK(T7) } \
    (OUT0) = gacc0; (OUT1) = gacc1; } while (0)

    float v0 = 0, v1 = 0, s0 = 0, s1 = 0;
    LOADSET(cA, A0,A1,A2,A3, b);                 // idx(0)
    LOADSET(cB, B0,B1,B2,B3, BATCH + b);         // idx(1)
    LOADSET(cC, C0,C1,C2,C3, 2 * BATCH + b);     // idx(2)
    LOADSET(cD, D0,D1,D2,D3, 3 * BATCH + b);     // idx(3)

    for (int t = 0; t < T_STEPS; t += 2) {
        const int rowA = t * BATCH + b;
        const int rowB = rowA + BATCH;
        float ca0, ca1, cb0, cb1;
        GATHER(ca0, ca1, cA, A0,A1,A2,A3, rowA);  // two independent gather
        GATHER(cb0, cb1, cB, B0,B1,B2,B3, rowB);  // streams -> 2x MLP

        // rotate prefetch: A<-idx(t+2), B<-idx(t+3); fetch t+4, t+5
        cA = cC; A0=C0; A1=C1; A2=C2; A3=C3;
        cB = cD; B0=D0; B1=D1; B2=D2; B3=D3;
        int r4 = t + 4; if (r4 > T_STEPS - 1) r4 = T_STEPS - 1;
        int r5 = t + 5; if (r5 > T_STEPS - 1) r5 = T_STEPS - 1;
        LOADSET(cC, C0,C1,C2,C3, r4 * BATCH + b);
        LOADSET(cD, D0,D1,D2,D3, r5 * BATCH + b);

        // ---- step t (identical math/order to rounds 1-7) ----
        ca0 += __shfl_xor(ca0, 32);
        ca1 += __shfl_xor(ca1, 32);
        s0 = __builtin_fmaf(s0, 0.875f, ca0);
        s1 = __builtin_fmaf(s1, 0.875f, ca1);
        v0 = __builtin_fmaf(0.125f, s0 - v0, v0);
        v1 = __builtin_fmaf(0.125f, s1 - v1, v1);
        unsigned long long m0 = __ballot(v0 > 1.0f);
        unsigned long long m1 = __ballot(v1 > 1.0f);
        if (v0 > 1.0f) v0 = 0.0f;
        if (v1 > 1.0f) v1 = 0.0f;
        if (l == 0) {
            uint2* zp = (uint2*)(zmask + (size_t)rowA * 32 + (tile << 1));
            *zp = make_uint2((uint32_t)m0, (uint32_t)m1);
        }
        // ---- step t+1 ----
        cb0 += __shfl_xor(cb0, 32);
        cb1 += __shfl_xor(cb1, 32);
        s0 = __builtin_fmaf(s0, 0.875f, cb0);
        s1 = __builtin_fmaf(s1, 0.875f, cb1);
        v0 = __builtin_fmaf(0.125f, s0 - v0, v0);
        v1 = __builtin_fmaf(0.125f, s1 - v1, v1);
        m0 = __ballot(v0 > 1.0f);
        m1 = __ballot(v1 > 1.0f);
        if (v0 > 1.0f) v0 = 0.0f;
        if (v1 > 1.0f) v1 = 0.0f;
        if (l == 0) {
            uint2* zp = (uint2*)(zmask + (size_t)rowB * 32 + (tile << 1));
            *zp = make_uint2((uint32_t)m0, (uint32_t)m1);
        }
    }
#undef LOADSET
#undef GCHUNK
#undef GATHER
}

// ---------------- Kernel 34: output synapse + LI scan, 4-way t-split ----------------
// r6-style sparse ctz scan (beat r7's branchless by ~84 us) + 4 time segments
// exploiting LI linearity: each segment runs from ZERO state (z-scan order
// per t unchanged), saves its zero-run end state (s,v); k_fix adds the
// homogeneous correction. 4x waves (8192, 4/SIMD LDS-capped) overlap the
// ~300-cyc/t dependent shfl+LI chain that made k_li ~400 us at 2/SIMD.
__global__ __launch_bounds__(256) void k_li(const uint32_t* __restrict__ zmask,
                                            const float* __restrict__ w_o,
                                            float* __restrict__ out,
                                            float2* __restrict__ svbuf) {
    extern __shared__ __align__(16) float wo[];   // 8 * 1025 floats = 32,800 B
    const int gb  = blockIdx.x;                   // seg(4) x b(128) x oct(4)
    const int seg = gb >> 9;
    const int rem = gb & 511;
    const int b   = rem >> 2;
    const int oct = rem & 3;
    const int o0  = oct << 3;
    const int tid = threadIdx.x;
    for (int lin = tid; lin < 8 * 1024; lin += 256) {
        int ol = lin >> 10, idx = lin & 1023;
        int word = idx >> 5, j = idx & 31;
        int h = ((word >> 1) << 6) + (j << 1) + (word & 1);  // zmask bit -> h
        wo[ol * 1025 + idx] = w_o[(size_t)(o0 + ol) * N_H + h];
    }
    __syncthreads();

    const int ol = tid >> 5, word = tid & 31;
    const float* wrow = wo + ol * 1025 + (word << 5);
    const int t0 = seg << 7, t1 = t0 + 128;

    float v = 0.0f, s = 0.0f;
    uint32_t m_n = zmask[(size_t)(t0 * BATCH + b) * 32 + word];
    for (int t = t0; t < t1; ++t) {
        uint32_t m = m_n;
        int tn = (t + 1 < t1) ? t + 1 : t;
        m_n = zmask[(size_t)(tn * BATCH + b) * 32 + word];

        float c = 0.0f;
        while (m) { int j = __builtin_ctz(m); m &= m - 1; c += wrow[j]; }

        c += __shfl_xor(c, 1);
        c += __shfl_xor(c, 2);
        c += __shfl_xor(c, 4);
        c += __shfl_xor(c, 8);
        c += __shfl_xor(c, 16);           // all 32 word-lanes hold full c

        s = __builtin_fmaf(s, 0.875f, c);
        v = __builtin_fmaf(0.125f, s - v, v);

        if (word == 0)
            out[(size_t)(t * BATCH + b) * 32 + o0 + ol] = v;
    }
    if (word == 0)                        // zero-run end state of this segment
        svbuf[((size_t)seg * BATCH + b) * 32 + o0 + ol] = make_float2(s, v);
}

// ---------------- Kernel F: add homogeneous LI correction for segs 1..3 ----------------
// M^k on (i,v): i->a^k i ; v->a^k v + 0.125 k a^k i  (a = 0.875, equal
// eigenvalues). True seg start = prev zero-run ends composed through M^128.
__global__ __launch_bounds__(256) void k_fix(const float2* __restrict__ svbuf,
                                             float* __restrict__ out) {
    int idx = blockIdx.x * 256 + threadIdx.x;     // 384*128*32 elements
    int o = idx & 31;
    int r = idx >> 5;
    int b = r & 127;
    int t = 128 + (r >> 7);                       // t in [128, 512)
    int seg = t >> 7;
    int k = (t & 127) + 1;
    const float A128 = 3.7714379e-8f;             // 0.875^128
    const float C128 = 6.0343007e-7f;             // 0.125*128*A128
    float2 S = svbuf[(size_t)b * 32 + o];         // true state entering seg 1
    if (seg >= 2) {
        float2 z = svbuf[((size_t)BATCH + b) * 32 + o];
        S = make_float2(z.x + A128 * S.x, z.y + A128 * S.y + C128 * S.x);
    }
    if (seg >= 3) {
        float2 z = svbuf[((size_t)2 * BATCH + b) * 32 + o];
        S = make_float2(z.x + A128 * S.x, z.y + A128 * S.y + C128 * S.x);
    }
    float ak = exp2f((float)k * -0.19264508f);    // 0.875^k
    float corr = __builtin_fmaf(ak, S.y, 0.125f * (float)k * ak * S.x);
    out[(size_t)(t * BATCH + b) * 32 + o] += corr;
}

// ---------------- launch ----------------
extern "C" void kernel_launch(void* const* d_in, const int* in_sizes, int n_in,
                              void* d_out, int out_size, void* d_ws, size_t ws_size,
                              hipStream_t stream) {
    const float* spikes = (const float*)d_in[0];
    const float* w_h    = (const float*)d_in[1];
    const float* w_o    = (const float*)d_in[2];
    float* out = (float*)d_out;

    char* ws = (char*)d_ws;
    uint32_t* pairs = (uint32_t*)(ws);                 // 8,388,608 B (k_lif only)
    uint32_t* cnts  = (uint32_t*)(ws + 8388608);       //   262,144 B (k_lif only)
    float*    w_t   = (float*)   (ws + 8650752);       // 1,048,576 B (k_lif only)
    uint32_t* zmask = (uint32_t*)(ws + 9699328);       // 8,388,608 B
    float2*   svbuf = (float2*)  (ws);                 //   131,072 B (reuses pairs
                                                       //   region; k_li/k_fix run
                                                       //   after k_lif, same stream)

    const int lds12 = (256 * 64 + 64) * 4;   // 65,792 B
    const int lds34 = 8 * 1025 * 4;          // 32,800 B
    hipFuncSetAttribute((const void*)k_lif, hipFuncAttributeMaxDynamicSharedMemorySize, lds12);
    hipFuncSetAttribute((const void*)k_li,  hipFuncAttributeMaxDynamicSharedMemorySize, lds34);

    k_prep<<<(T_STEPS * BATCH) / 16, 256, 0, stream>>>(spikes, pairs, cnts);
    k_tr<<<(N_H * N_IN) / 256, 256, 0, stream>>>(w_h, w_t);
    k_lif<<<256, 512, lds12, stream>>>(pairs, cnts, w_t, zmask);
    k_li<<<4 * BATCH * 4, 256, lds34, stream>>>(zmask, w_o, out, svbuf);
    k_fix<<<(384 * BATCH * N_OUT) / 256, 256, 0, stream>>>(svbuf, out);
}